// Round 11
// baseline (134.641 us; speedup 1.0000x reference)
//
#include <hip/hip_runtime.h>
#include <hip/hip_fp16.h>

#define Tt 64
#define Ee 128
#define Aa 10
#define Vv 32001

typedef __attribute__((ext_vector_type(8))) _Float16 half8;
typedef __attribute__((ext_vector_type(4))) _Float16 half4;
typedef __attribute__((ext_vector_type(4))) float f32x4;

#define L2E 1.44269504f

__device__ __forceinline__ float fast_rcp(float x) { return __builtin_amdgcn_rcpf(x); }
__device__ __forceinline__ float fast_exp2(float x) {
#if __has_builtin(__builtin_amdgcn_exp2f)
    return __builtin_amdgcn_exp2f(x);
#else
    return __expf(x * 0.69314718056f);
#endif
}

__device__ __forceinline__ half8 load_h8(const float* p) {
    f32x4 a = *(const f32x4*)p;
    f32x4 b = *(const f32x4*)(p + 4);
    half8 r;
    r[0] = (_Float16)a[0]; r[1] = (_Float16)a[1]; r[2] = (_Float16)a[2]; r[3] = (_Float16)a[3];
    r[4] = (_Float16)b[0]; r[5] = (_Float16)b[1]; r[6] = (_Float16)b[2]; r[7] = (_Float16)b[3];
    return r;
}
__device__ __forceinline__ half8 load_h8s(const float* p, float s) {
    f32x4 a = *(const f32x4*)p;
    f32x4 b = *(const f32x4*)(p + 4);
    half8 r;
#pragma unroll
    for (int j = 0; j < 4; ++j) { r[j] = (_Float16)(a[j] * s); r[4 + j] = (_Float16)(b[j] * s); }
    return r;
}

#define MFMA_F16(a, b, c)  __builtin_amdgcn_mfma_f32_16x16x32_f16(a, b, c, 0, 0, 0)

// lgkm-only barrier: DS traffic drained (cross-wave h exchange); vmem gathers
// stay in flight across the barrier (consumed at their natural use next step).
#define BAR_LGKM() do { \
    asm volatile("s_waitcnt lgkmcnt(0)" ::: "memory"); \
    __builtin_amdgcn_s_barrier(); \
} while (0)

// ============================================================================
// Precompute (folded 3-gate): gi table layout _Float16[v][128][4] = {r',z',n',0}
// r' = -log2e*(emb@wr + bir + bhr), z' likewise, n' = 2log2e*(emb@wn + bin).
// ============================================================================
__global__ __launch_bounds__(512, 2) void gi_precompute(
    const float* __restrict__ emb, const float* __restrict__ w_ih,
    const float* __restrict__ b_ih, const float* __restrict__ b_hh,
    char* __restrict__ gw) {
    __shared__ __align__(16) char xs[8192];  // [32][128] f16 swizzled
    const int tid = threadIdx.x;
    const int wv = tid >> 6;
    const int ln = tid & 63;
    const int fn = ln & 15;
    const int kg = ln >> 4;
    const int v0 = blockIdx.x * 32;
    const int gc = wv * 16 + fn;
    const int srow = tid >> 4;
    const int c8 = (tid & 15) << 3;

    {
        int v = v0 + srow; if (v >= Vv) v = Vv - 1;
        half8 hx = load_h8(emb + (size_t)v * Ee + c8);
        int off = (srow * 256 + c8 * 2) ^ ((srow & 7) << 4);
        *(half8*)(xs + off) = hx;
    }
    half8 wr[4], wz[4], wn[4];
#pragma unroll
    for (int kt = 0; kt < 4; ++kt) {
        int k0 = kt * 32 + kg * 8;
        wr[kt] = load_h8(w_ih + (size_t)gc * Ee + k0);
        wz[kt] = load_h8(w_ih + (size_t)(128 + gc) * Ee + k0);
        wn[kt] = load_h8(w_ih + (size_t)(256 + gc) * Ee + k0);
    }
    const float bcr = b_ih[gc] + b_hh[gc];
    const float bcz = b_ih[128 + gc] + b_hh[128 + gc];
    const float bcn = b_ih[256 + gc];
    __syncthreads();

    f32x4 ar[2], az[2], an[2];
#pragma unroll
    for (int mt = 0; mt < 2; ++mt) {
        ar[mt] = (f32x4){0.f, 0.f, 0.f, 0.f};
        az[mt] = (f32x4){0.f, 0.f, 0.f, 0.f};
        an[mt] = (f32x4){0.f, 0.f, 0.f, 0.f};
    }
#pragma unroll
    for (int kt = 0; kt < 4; ++kt)
#pragma unroll
        for (int mt = 0; mt < 2; ++mt) {
            int r = mt * 16 + fn;
            int off = (r * 256 + (kt * 32 + kg * 8) * 2) ^ ((r & 7) << 4);
            half8 ha = *(const half8*)(xs + off);
            ar[mt] = MFMA_F16(ha, wr[kt], ar[mt]);
            az[mt] = MFMA_F16(ha, wz[kt], az[mt]);
            an[mt] = MFMA_F16(ha, wn[kt], an[mt]);
        }
#pragma unroll
    for (int mt = 0; mt < 2; ++mt)
#pragma unroll
        for (int i = 0; i < 4; ++i) {
            int v = v0 + mt * 16 + kg * 4 + i;
            if (v < Vv) {
                half4 g;
                g[0] = (_Float16)((ar[mt][i] + bcr) * (-L2E));
                g[1] = (_Float16)((az[mt][i] + bcz) * (-L2E));
                g[2] = (_Float16)((an[mt][i] + bcn) * (2.f * L2E));
                g[3] = (_Float16)0.f;
                *(half4*)(gw + (size_t)v * 1024 + gc * 8) = g;
            }
        }
}

// ============================================================================
// Main: 16 rows/block, 4 waves (256 thr), wave owns 32 cols = two 16-col tiles.
// Grid 512 -> 2 independent blocks/CU: cross-block overlap fills barrier waits
// (no intra-block skew needed -> ONE lgkm-only barrier per step).
// LDS (13120 B): tokb [16][64] int 0..4096 | H0 4096 | H1 8192 |
//                lg 12288..13056 | tstar 13056..13120
//                (epilogue outst f32 [16][128] aliases 4096..12288)
// ============================================================================
#define SM_BYTES 13120

__global__ __launch_bounds__(256, 2) void gru_quad_kernel(
    const int* __restrict__ utt, const char* __restrict__ gwc,
    const float* __restrict__ w_hh, const float* __restrict__ b_hh,
    const float* __restrict__ w_out, const float* __restrict__ b_out,
    float* __restrict__ out) {
    __shared__ __align__(16) char smem[SM_BYTES];
    int* tokb = (int*)smem;
    float* lg = (float*)(smem + 12288);
    int* tstar = (int*)(smem + 13056);
    float* outst = (float*)(smem + 4096);

    const int tid = threadIdx.x;
    const int wv = tid >> 6;          // wave 0..3
    const int ln = tid & 63;
    const int fn = ln & 15;
    const int kg = ln >> 4;
    const int row0 = blockIdx.x * 16;
    const int gc0 = wv * 32 + fn;     // col tile 0
    const int gc1 = gc0 + 16;         // col tile 1

    // ---- prologue ----
    if (tid < 16) tstar[tid] = Tt - 1;
    *(f32x4*)(smem + 4096 + tid * 16) = (f32x4){0.f, 0.f, 0.f, 0.f};  // H0 = h(-1) = 0
    __syncthreads();
    {
        // 16 rows * 64 tokens = 1024 ints -> int4 per thread
        int4 tv = ((const int4*)(utt + (size_t)row0 * Tt))[tid];
        int4 sv = {tv.x << 10, tv.y << 10, tv.z << 10, tv.w << 10};  // byte offsets
        ((int4*)tokb)[tid] = sv;
        int row = tid >> 4;
        int tq = (tid & 15) << 2;
        if (tv.x == 0) atomicMin(&tstar[row], tq);
        if (tv.y == 0) atomicMin(&tstar[row], tq + 1);
        if (tv.z == 0) atomicMin(&tstar[row], tq + 2);
        if (tv.w == 0) atomicMin(&tstar[row], tq + 3);
    }
    half8 whr[2][4], whz[2][4], whn[2][4];
#pragma unroll
    for (int kt = 0; kt < 4; ++kt) {
        int k0 = kt * 32 + kg * 8;
        whr[0][kt] = load_h8s(w_hh + (size_t)gc0 * Ee + k0, -L2E);
        whr[1][kt] = load_h8s(w_hh + (size_t)gc1 * Ee + k0, -L2E);
        whz[0][kt] = load_h8s(w_hh + (size_t)(128 + gc0) * Ee + k0, -L2E);
        whz[1][kt] = load_h8s(w_hh + (size_t)(128 + gc1) * Ee + k0, -L2E);
        whn[0][kt] = load_h8s(w_hh + (size_t)(256 + gc0) * Ee + k0, 2.f * L2E);
        whn[1][kt] = load_h8s(w_hh + (size_t)(256 + gc1) * Ee + k0, 2.f * L2E);
    }
    const float bhn2_0 = b_hh[256 + gc0] * (2.f * L2E);
    const float bhn2_1 = b_hh[256 + gc1] * (2.f * L2E);
    __syncthreads();   // tokb + tstar ready

    int offk[4], wof[2][4];
#pragma unroll
    for (int kt = 0; kt < 4; ++kt)
        offk[kt] = (fn * 256 + (kt * 32 + kg * 8) * 2) ^ ((fn & 7) << 4);
#pragma unroll
    for (int i = 0; i < 4; ++i) {
        int row = kg * 4 + i;
        wof[0][i] = (row * 256 + gc0 * 2) ^ ((row & 7) << 4);
        wof[1][i] = (row * 256 + gc1 * 2) ^ ((row & 7) << 4);
    }

    int ts[4];
#pragma unroll
    for (int i = 0; i < 4; ++i) ts[i] = tstar[kg * 4 + i];

    // gi(0) straight into registers
    half4 g0[4], g1[4];
#pragma unroll
    for (int i = 0; i < 4; ++i) {
        int to = tokb[(kg * 4 + i) * 64];
        g0[i] = *(const half4*)(gwc + to + gc0 * 8);
        g1[i] = *(const half4*)(gwc + to + gc1 * 8);
    }

    f32x4 h0 = (f32x4){0.f, 0.f, 0.f, 0.f}, o0 = h0;
    f32x4 h1 = h0, o1 = h0;

#pragma unroll 1
    for (int k = 0; k < Tt; ++k) {
        const char* hRd = smem + 4096 + (k & 1) * 4096;
        char* hWr = smem + 4096 + ((k + 1) & 1) * 4096;
        // ---- h-frag reads (rows x K, shared by both col tiles) ----
        half8 f[4];
#pragma unroll
        for (int kt = 0; kt < 4; ++kt) f[kt] = *(const half8*)(hRd + offk[kt]);
        // ---- issue gathers gi(k+1); vmem spans the barrier, consumed next iter ----
        int t2 = (k < Tt - 1) ? k + 1 : Tt - 1;
        half4 gn0[4], gn1[4];
#pragma unroll
        for (int i = 0; i < 4; ++i) {
            int to = tokb[(kg * 4 + i) * 64 + t2];
            gn0[i] = *(const half4*)(gwc + to + gc0 * 8);
            gn1[i] = *(const half4*)(gwc + to + gc1 * 8);
        }
        // ---- C-init from gi(k) (cvts fill the ds_read latency) ----
        f32x4 ar0, az0, an0, ar1, az1, an1;
#pragma unroll
        for (int i = 0; i < 4; ++i) {
            ar0[i] = (float)g0[i][0]; az0[i] = (float)g0[i][1]; an0[i] = bhn2_0;
            ar1[i] = (float)g1[i][0]; az1[i] = (float)g1[i][1]; an1[i] = bhn2_1;
        }
        __builtin_amdgcn_s_setprio(1);
#pragma unroll
        for (int kt = 0; kt < 4; ++kt) {
            ar0 = MFMA_F16(f[kt], whr[0][kt], ar0);
            az0 = MFMA_F16(f[kt], whz[0][kt], az0);
            an0 = MFMA_F16(f[kt], whn[0][kt], an0);
            ar1 = MFMA_F16(f[kt], whr[1][kt], ar1);
            az1 = MFMA_F16(f[kt], whz[1][kt], az1);
            an1 = MFMA_F16(f[kt], whn[1][kt], an1);
        }
        __builtin_amdgcn_s_setprio(0);
        // ---- gates for both col tiles; write h(k) to next buffer ----
        bool wr = (k < Tt - 1);
#pragma unroll
        for (int i = 0; i < 4; ++i) {
            float ea = fast_exp2(ar0[i]);
            float eb = fast_exp2(az0[i]);
            float da = 1.f + ea, db = 1.f + eb;
            float R = fast_rcp(da * db);
            float rr = db * R, zz = da * R;
            float pnp = (float)g0[i][2] + rr * an0[i];
            float ec = fast_exp2(pnp);
            float nn = 1.f - 2.f * fast_rcp(ec + 1.f);
            float h = nn + zz * (h0[i] - nn);
            h0[i] = h;
            if (k == ts[i]) o0[i] = h;
            if (wr) *(_Float16*)(hWr + wof[0][i]) = (_Float16)h;
        }
#pragma unroll
        for (int i = 0; i < 4; ++i) {
            float ea = fast_exp2(ar1[i]);
            float eb = fast_exp2(az1[i]);
            float da = 1.f + ea, db = 1.f + eb;
            float R = fast_rcp(da * db);
            float rr = db * R, zz = da * R;
            float pnp = (float)g1[i][2] + rr * an1[i];
            float ec = fast_exp2(pnp);
            float nn = 1.f - 2.f * fast_rcp(ec + 1.f);
            float h = nn + zz * (h1[i] - nn);
            h1[i] = h;
            if (k == ts[i]) o1[i] = h;
            if (wr) *(_Float16*)(hWr + wof[1][i]) = (_Float16)h;
        }
#pragma unroll
        for (int i = 0; i < 4; ++i) { g0[i] = gn0[i]; g1[i] = gn1[i]; }
        BAR_LGKM();  // h(k) visible; gi gathers stay in flight
    }

    // ---- epilogue: logits + softmax (outst aliases H buffers; reads drained) ----
#pragma unroll
    for (int i = 0; i < 4; ++i) {
        outst[(kg * 4 + i) * Ee + gc0] = o0[i];
        outst[(kg * 4 + i) * Ee + gc1] = o1[i];
    }
    __syncthreads();

    if (tid < 16 * Aa) {
        int r = tid / Aa, a = tid % Aa;
        const float* wo = w_out + a * Ee;
        const float* os = outst + r * Ee;
        float s = b_out[a];
#pragma unroll
        for (int j = 0; j < Ee; j += 4) {
            f32x4 o = *(const f32x4*)(os + j);
            f32x4 w4 = *(const f32x4*)(wo + j);
            s += o[0] * w4[0] + o[1] * w4[1] + o[2] * w4[2] + o[3] * w4[3];
        }
        lg[r * 12 + a] = s;
    }
    __syncthreads();
    if (tid < 16) {
        float v[Aa];
        float mx = -1e30f;
#pragma unroll
        for (int a = 0; a < Aa; ++a) {
            v[a] = lg[tid * 12 + a];
            mx = fmaxf(mx, v[a]);
        }
        float sum = 0.f;
#pragma unroll
        for (int a = 0; a < Aa; ++a) {
            v[a] = __expf(v[a] - mx);
            sum += v[a];
        }
        float inv = fast_rcp(sum);
#pragma unroll
        for (int a = 0; a < Aa; ++a) out[(size_t)(row0 + tid) * Aa + a] = v[a] * inv;
    }
}

// ============================================================================
// Fallback (R5 kernel) if ws can't hold the gi table.
// ============================================================================
#define FSM_BYTES 21312
__global__ __launch_bounds__(512, 2) void gru_fallback_kernel(
    const int* __restrict__ utt, const float* __restrict__ emb,
    const float* __restrict__ w_ih, const float* __restrict__ w_hh,
    const float* __restrict__ b_ih, const float* __restrict__ b_hh,
    const float* __restrict__ w_out, const float* __restrict__ b_out,
    float* __restrict__ out) {
    __shared__ __align__(16) char smem[FSM_BYTES];
    int* tokb = (int*)smem;
    float* lg = (float*)(smem + 20480);
    int* tstar = (int*)(smem + 21248);
    float* outst = (float*)(smem + 4096);

    const int tid = threadIdx.x;
    const int wv = tid >> 6;
    const int ln = tid & 63;
    const int fn = ln & 15;
    const int kg = ln >> 4;
    const int row0 = blockIdx.x * 16;
    const int gc = wv * 16 + fn;
    const int srow = tid >> 5;
    const int c4 = (tid & 31) << 2;

    if (tid < 16) tstar[tid] = Tt - 1;
    *(float2*)(smem + 12288 + tid * 8) = (float2){0.f, 0.f};
    __syncthreads();
    {
        int2 tv = ((const int2*)(utt + (size_t)row0 * Tt))[tid];
        ((int2*)tokb)[tid] = tv;
        int row = tid >> 5;
        int tq = (tid & 31) << 1;
        if (tv.x == 0) atomicMin(&tstar[row], tq);
        if (tv.y == 0) atomicMin(&tstar[row], tq + 1);
    }
    half8 wir[4], wiz[4], win[4], whr[4], whz[4], whn[4];
#pragma unroll
    for (int kt = 0; kt < 4; ++kt) {
        int k0 = kt * 32 + kg * 8;
        wir[kt] = load_h8(w_ih + (size_t)gc * Ee + k0);
        wiz[kt] = load_h8(w_ih + (size_t)(128 + gc) * Ee + k0);
        win[kt] = load_h8(w_ih + (size_t)(256 + gc) * Ee + k0);
        whr[kt] = load_h8(w_hh + (size_t)gc * Ee + k0);
        whz[kt] = load_h8(w_hh + (size_t)(128 + gc) * Ee + k0);
        whn[kt] = load_h8(w_hh + (size_t)(256 + gc) * Ee + k0);
    }
    const float bcr = b_ih[gc] + b_hh[gc];
    const float bcz = b_ih[128 + gc] + b_hh[128 + gc];
    const float bin = b_ih[256 + gc];
    const float bhn = b_hh[256 + gc];
    __syncthreads();
    int ts[4];
#pragma unroll
    for (int i = 0; i < 4; ++i) ts[i] = tstar[kg * 4 + i];
    {
        int tok = tokb[srow * Tt];
        f32x4 a = *(const f32x4*)(emb + (size_t)tok * Ee + c4);
        half4 hx;
#pragma unroll
        for (int j = 0; j < 4; ++j) hx[j] = (_Float16)a[j];
        int off = (srow * 256 + c4 * 2) ^ ((srow & 7) << 4);
        *(half4*)(smem + 4096 + off) = hx;
    }
    __syncthreads();
    f32x4 hreg = (f32x4){0.f, 0.f, 0.f, 0.f};
    f32x4 oreg = (f32x4){0.f, 0.f, 0.f, 0.f};
    int cur = 0;
#pragma unroll 1
    for (int t = 0; t < Tt; ++t) {
        f32x4 pa;
        if (t < Tt - 1) {
            int tok = tokb[srow * Tt + t + 1];
            pa = *(const f32x4*)(emb + (size_t)tok * Ee + c4);
        }
        const char* xb = smem + 4096 + cur * 4096;
        const char* hb = smem + 12288 + cur * 4096;
        f32x4 ar = (f32x4){0.f, 0.f, 0.f, 0.f};
        f32x4 az = (f32x4){0.f, 0.f, 0.f, 0.f};
        f32x4 ain = (f32x4){0.f, 0.f, 0.f, 0.f};
        f32x4 ahn = (f32x4){0.f, 0.f, 0.f, 0.f};
        __builtin_amdgcn_s_setprio(1);
#pragma unroll
        for (int kt = 0; kt < 4; ++kt) {
            int off = (fn * 256 + (kt * 32 + kg * 8) * 2) ^ ((fn & 7) << 4);
            half8 xa = *(const half8*)(xb + off);
            half8 ha = *(const half8*)(hb + off);
            ar = MFMA_F16(xa, wir[kt], ar);
            ar = MFMA_F16(ha, whr[kt], ar);
            az = MFMA_F16(xa, wiz[kt], az);
            az = MFMA_F16(ha, whz[kt], az);
            ain = MFMA_F16(xa, win[kt], ain);
            ahn = MFMA_F16(ha, whn[kt], ahn);
        }
        __builtin_amdgcn_s_setprio(0);
        char* hn = smem + 12288 + (cur ^ 1) * 4096;
#pragma unroll
        for (int i = 0; i < 4; ++i) {
            float pr = ar[i] + bcr;
            float pz = az[i] + bcz;
            float rr = fast_rcp(1.f + __expf(-pr));
            float zz = fast_rcp(1.f + __expf(-pz));
            float pn = ain[i] + bin + rr * (ahn[i] + bhn);
            float e2 = __expf(2.f * pn);
            float nn = 1.f - 2.f * fast_rcp(e2 + 1.f);
            float h = (1.f - zz) * nn + zz * hreg[i];
            hreg[i] = h;
            if (t == ts[i]) oreg[i] = h;
            if (t < Tt - 1) {
                int row = kg * 4 + i;
                int off = (row * 256 + gc * 2) ^ ((row & 7) << 4);
                *(_Float16*)(hn + off) = (_Float16)h;
            }
        }
        if (t < Tt - 1) {
            half4 hx;
#pragma unroll
            for (int j = 0; j < 4; ++j) hx[j] = (_Float16)pa[j];
            int off = (srow * 256 + c4 * 2) ^ ((srow & 7) << 4);
            *(half4*)(smem + 4096 + (cur ^ 1) * 4096 + off) = hx;
        }
        __syncthreads();
        cur ^= 1;
    }
#pragma unroll
    for (int i = 0; i < 4; ++i) outst[(kg * 4 + i) * Ee + gc] = oreg[i];
    __syncthreads();
    if (tid < 16 * Aa) {
        int r = tid / Aa, a = tid % Aa;
        const float* wo = w_out + a * Ee;
        const float* os = outst + r * Ee;
        float s = b_out[a];
#pragma unroll
        for (int j = 0; j < Ee; j += 4) {
            f32x4 o = *(const f32x4*)(os + j);
            f32x4 w4 = *(const f32x4*)(wo + j);
            s += o[0] * w4[0] + o[1] * w4[1] + o[2] * w4[2] + o[3] * w4[3];
        }
        lg[r * 12 + a] = s;
    }
    __syncthreads();
    if (tid < 16) {
        float v[Aa];
        float mx = -1e30f;
#pragma unroll
        for (int a = 0; a < Aa; ++a) {
            v[a] = lg[tid * 12 + a];
            mx = fmaxf(mx, v[a]);
        }
        float sum = 0.f;
#pragma unroll
        for (int a = 0; a < Aa; ++a) {
            v[a] = __expf(v[a] - mx);
            sum += v[a];
        }
        float inv = fast_rcp(sum);
#pragma unroll
        for (int a = 0; a < Aa; ++a) out[(size_t)(row0 + tid) * Aa + a] = v[a] * inv;
    }
}

extern "C" void kernel_launch(void* const* d_in, const int* in_sizes, int n_in,
                              void* d_out, int out_size, void* d_ws, size_t ws_size,
                              hipStream_t stream) {
    (void)in_sizes; (void)n_in; (void)out_size;
    const int* utt = (const int*)d_in[0];
    const float* emb = (const float*)d_in[2];
    const float* wih = (const float*)d_in[3];
    const float* whh = (const float*)d_in[4];
    const float* bih = (const float*)d_in[5];
    const float* bhh = (const float*)d_in[6];
    const float* wout = (const float*)d_in[7];
    const float* bout = (const float*)d_in[8];
    const size_t need = (size_t)Vv * 1024;  // 32.77 MB
    if (ws_size >= need) {
        char* gw = (char*)d_ws;
        gi_precompute<<<dim3((Vv + 31) / 32), 512, 0, stream>>>(emb, wih, bih, bhh, gw);
        gru_quad_kernel<<<512, 256, 0, stream>>>(utt, gw, whh, bhh, wout, bout, (float*)d_out);
    } else {
        gru_fallback_kernel<<<512, 512, 0, stream>>>(utt, emb, wih, whh, bih, bhh, wout, bout,
                                                     (float*)d_out);
    }
}